// Round 1
// baseline (845.955 us; speedup 1.0000x reference)
//
#include <hip/hip_runtime.h>

#define B_ 256
#define T_ 1024
#define E_ 32
#define H_ 128
#define NOBS_ 1048576
#define RPB 4                 // batch rows per LSTM block
#define NBLK (B_ / RPB)       // 64
#define NW 8                  // waves per block
#define THREADS (NW * 64)     // 512

typedef __attribute__((ext_vector_type(8))) short bf16x8;
typedef __attribute__((ext_vector_type(4))) float f32x4;

__device__ __forceinline__ short f2bf(float x) {
    unsigned u = __float_as_uint(x);
    unsigned r = u + 0x7FFFu + ((u >> 16) & 1u);   // round-to-nearest-even
    return (short)(r >> 16);
}

__device__ __forceinline__ float fast_sigmoid(float x) {
    float e = __expf(-x);
    return __builtin_amdgcn_rcpf(1.0f + e);
}

__device__ __forceinline__ float fast_tanh(float x) {
    float e = __expf(2.0f * x);                    // inf for big x -> rcp=0 -> 1.0 (correct)
    return 1.0f - 2.0f * __builtin_amdgcn_rcpf(e + 1.0f);
}

// ---------------- embedding kernel ----------------
// one thread per slot s in [0, B*T): binary search sorted obs_slot for the
// segment, sum obs_emb rows; action slots take action_emb row instead.
__global__ void embed_kernel(const int* __restrict__ obs_ids,
                             const int* __restrict__ obs_slot,
                             const int* __restrict__ action_ids,
                             const int* __restrict__ is_action,
                             const float* __restrict__ action_emb,
                             const float* __restrict__ obs_emb,
                             float* __restrict__ embedded) {
    __shared__ float s_act[5 * E_];
    __shared__ float s_obs[11 * E_];
    for (int i = threadIdx.x; i < 5 * E_; i += blockDim.x) s_act[i] = action_emb[i];
    for (int i = threadIdx.x; i < 11 * E_; i += blockDim.x) s_obs[i] = obs_emb[i];
    __syncthreads();

    int s = blockIdx.x * blockDim.x + threadIdx.x;
    if (s >= B_ * T_) return;

    float acc[E_];
    if (is_action[s]) {
        int a = action_ids[s];
        #pragma unroll
        for (int e = 0; e < E_; e++) acc[e] = s_act[a * E_ + e];
    } else {
        #pragma unroll
        for (int e = 0; e < E_; e++) acc[e] = 0.0f;
        // lower_bound(obs_slot, s)
        int lo = 0, hi = NOBS_;
        while (lo < hi) {
            int mid = (lo + hi) >> 1;
            if (obs_slot[mid] < s) lo = mid + 1; else hi = mid;
        }
        int j = lo;
        while (j < NOBS_ && obs_slot[j] == s) {
            int id = obs_ids[j];
            #pragma unroll
            for (int e = 0; e < E_; e++) acc[e] += s_obs[id * E_ + e];
            j++;
        }
    }
    float4* dst = (float4*)(embedded + (size_t)s * E_);
    #pragma unroll
    for (int q = 0; q < E_ / 4; q++) {
        float4 v; v.x = acc[4*q]; v.y = acc[4*q+1]; v.z = acc[4*q+2]; v.w = acc[4*q+3];
        dst[q] = v;
    }
}

// ---------------- LSTM kernel ----------------
// block = 512 threads (8 waves) handles RPB=4 batch rows for all T steps.
// wave w owns h-cols [16w,16w+16): computes i/f/g/o gate tiles via MFMA with
// weights resident in VGPRs. gates bounce through LDS; dense thread t owns
// (r = t&3, col = t>>2) with c,h persistent in registers.
#define LROW 168   // in_lds row length (bf16): 32 x + 128 h + 8 pad (336B: 2-way banks)

__launch_bounds__(THREADS, 2)
__global__ void lstm_kernel(const float* __restrict__ embedded,
                            const int* __restrict__ lengths,
                            const float* __restrict__ W_ih,
                            const float* __restrict__ W_hh,
                            const float* __restrict__ b_ih,
                            const float* __restrict__ b_hh,
                            float* __restrict__ outputs,
                            float* __restrict__ h_out,
                            float* __restrict__ c_out) {
    __shared__ __align__(16) short in_lds[16 * LROW];      // rows 0..15; k: 0..31 x, 32..159 h
    __shared__ __align__(16) float gates_lds[512 * RPB];   // [gatecol 0..511][row 0..3]

    const int tid  = threadIdx.x;
    const int lane = tid & 63;
    const int wave = tid >> 6;
    const int row0 = blockIdx.x * RPB;

    // ---- persistent weight fragments (B operand): wave w, gate gt, K-tile kt ----
    // B[k][col]: col = lane&15 within tile, k = (lane>>4)*8 + j
    const int col16 = (wave << 4) + (lane & 15);
    const int kgrp  = (lane >> 4) * 8;
    bf16x8 wfrag[4][5];
    #pragma unroll
    for (int gt = 0; gt < 4; gt++) {
        int gcol = gt * H_ + col16;
        {
            const float* p = W_ih + (size_t)gcol * E_ + kgrp;
            bf16x8 v;
            #pragma unroll
            for (int j = 0; j < 8; j++) v[j] = f2bf(p[j]);
            wfrag[gt][0] = v;
        }
        #pragma unroll
        for (int kt = 1; kt < 5; kt++) {
            const float* q = W_hh + (size_t)gcol * H_ + (kt - 1) * 32 + kgrp;
            bf16x8 v;
            #pragma unroll
            for (int j = 0; j < 8; j++) v[j] = f2bf(q[j]);
            wfrag[gt][kt] = v;
        }
    }

    // ---- dense-thread persistent state: (r, col) ----
    const int dr   = tid & (RPB - 1);     // 0..3
    const int dcol = tid >> 2;            // 0..127
    const int grow = row0 + dr;           // global batch row
    const int len  = lengths[grow];
    const float bias_i = b_ih[0 * H_ + dcol] + b_hh[0 * H_ + dcol];
    const float bias_f = b_ih[1 * H_ + dcol] + b_hh[1 * H_ + dcol];
    const float bias_g = b_ih[2 * H_ + dcol] + b_hh[2 * H_ + dcol];
    const float bias_o = b_ih[3 * H_ + dcol] + b_hh[3 * H_ + dcol];
    float c_reg = 0.0f, h_reg = 0.0f;

    // x loader: threads 0..127 -> (lr = tid>>5 in 0..3, le = tid&31)
    const float* emb_base = embedded + ((size_t)(row0 + (tid >> 5)) * T_) * E_ + (tid & 31);

    // init LDS: zeros (h=0, pad rows 4..15 = 0), then x for t=0
    for (int i = tid; i < 16 * LROW; i += THREADS) in_lds[i] = 0;
    __syncthreads();
    if (tid < 128) in_lds[(tid >> 5) * LROW + (tid & 31)] = f2bf(emb_base[0]);
    __syncthreads();

    const int qrow = lane & 15;           // A row
    float* out_ptr = outputs + (size_t)grow * T_ * H_ + dcol;

    for (int t = 0; t < T_; ++t) {
        // P1: A fragments from LDS (x + h), k = kt*32 + kgrp .. +7
        bf16x8 a[5];
        #pragma unroll
        for (int kt = 0; kt < 5; kt++)
            a[kt] = *(const bf16x8*)&in_lds[qrow * LROW + kt * 32 + kgrp];

        // P2: 20 MFMAs (4 gate tiles x 5 K-tiles)
        f32x4 acc[4];
        #pragma unroll
        for (int gt = 0; gt < 4; gt++) acc[gt] = (f32x4)(0.0f);
        #pragma unroll
        for (int kt = 0; kt < 5; kt++)
            #pragma unroll
            for (int gt = 0; gt < 4; gt++)
                acc[gt] = __builtin_amdgcn_mfma_f32_16x16x32_bf16(a[kt], wfrag[gt][kt], acc[gt], 0, 0, 0);

        // P3: prefetch next x (hides HBM latency under barrier+P4), write gates
        float xn = 0.0f;
        if (tid < 128 && t + 1 < T_) xn = emb_base[(size_t)(t + 1) * E_];
        if (lane < 16) {   // only lane-group 0 holds real rows 0..3 (RPB=4)
            #pragma unroll
            for (int gt = 0; gt < 4; gt++) {
                float4 v; v.x = acc[gt][0]; v.y = acc[gt][1]; v.z = acc[gt][2]; v.w = acc[gt][3];
                *(float4*)&gates_lds[(gt * H_ + col16) * RPB] = v;
            }
        }
        __syncthreads();

        // P4: dense elementwise (bank-perfect reads: dword index == tid mod pattern)
        float gi = gates_lds[(0 * H_ + dcol) * RPB + dr] + bias_i;
        float gf = gates_lds[(1 * H_ + dcol) * RPB + dr] + bias_f;
        float gg = gates_lds[(2 * H_ + dcol) * RPB + dr] + bias_g;
        float go = gates_lds[(3 * H_ + dcol) * RPB + dr] + bias_o;
        float i_ = fast_sigmoid(gi);
        float f_ = fast_sigmoid(gf);
        float g_ = fast_tanh(gg);
        float o_ = fast_sigmoid(go);
        float c_new = f_ * c_reg + i_ * g_;
        float h_new = o_ * fast_tanh(c_new);
        bool m = (t < len);
        c_reg = m ? c_new : c_reg;
        h_reg = m ? h_new : h_reg;
        out_ptr[(size_t)t * H_] = m ? h_new : 0.0f;

        // feed back h (bf16) for next step's A fragments
        in_lds[dr * LROW + 32 + dcol] = f2bf(h_reg);
        // write prefetched x
        if (tid < 128) in_lds[(tid >> 5) * LROW + (tid & 31)] = f2bf(xn);
        __syncthreads();
    }

    // final states
    h_out[(size_t)grow * H_ + dcol] = h_reg;
    c_out[(size_t)grow * H_ + dcol] = c_reg;
}

extern "C" void kernel_launch(void* const* d_in, const int* in_sizes, int n_in,
                              void* d_out, int out_size, void* d_ws, size_t ws_size,
                              hipStream_t stream) {
    const int*   obs_ids       = (const int*)d_in[0];
    const int*   obs_slot      = (const int*)d_in[1];
    const int*   action_ids    = (const int*)d_in[2];
    const int*   is_action     = (const int*)d_in[3];
    const int*   input_lengths = (const int*)d_in[4];
    const float* action_emb    = (const float*)d_in[5];
    const float* obs_emb       = (const float*)d_in[6];
    const float* W_ih          = (const float*)d_in[7];
    const float* W_hh          = (const float*)d_in[8];
    const float* b_ih          = (const float*)d_in[9];
    const float* b_hh          = (const float*)d_in[10];

    float* out      = (float*)d_out;
    float* outputs  = out;                                   // [B,T,H]
    float* h_out    = out + (size_t)B_ * T_ * H_;            // [1,B,H]
    float* c_out    = h_out + (size_t)B_ * H_;               // [1,B,H]
    float* embedded = c_out + (size_t)B_ * H_;               // [B,T,E]

    hipLaunchKernelGGL(embed_kernel, dim3((B_ * T_ + 255) / 256), dim3(256), 0, stream,
                       obs_ids, obs_slot, action_ids, is_action, action_emb, obs_emb, embedded);

    hipLaunchKernelGGL(lstm_kernel, dim3(NBLK), dim3(THREADS), 0, stream,
                       embedded, input_lengths, W_ih, W_hh, b_ih, b_hh,
                       outputs, h_out, c_out);
}